// Round 13
// baseline (947.487 us; speedup 1.0000x reference)
//
#include <hip/hip_runtime.h>
#include <math.h>
#include <stdint.h>

// B=4, H=16, N=4096, D=128 -> 64 independent scan rows of length 4096.
static constexpr int ROWS = 64;
static constexpr int NSEQ = 4096;
static constexpr int DIM  = 128;
static constexpr int SC   = 16;              // scalar sub-chunk length
static constexpr int SPR  = NSEQ / SC;       // 256 sub-chunks per row
static constexpr int NSC  = ROWS * SPR;      // 16384 sub-chunks
static constexpr int VC   = 64;              // vector chunk length
static constexpr int VPR  = NSEQ / VC;       // 64 chunks per row
static constexpr int NVC  = ROWS * VPR;      // 4096 vector chunks
static constexpr int SPC  = VC / SC;         // sub-chunks per vector chunk = 4

typedef __attribute__((address_space(3))) uint32_t  lds_u32;
typedef const __attribute__((address_space(1))) uint32_t g_u32;

// ---------------------------------------------------------------------------
// k_alpha (R10-v8, best measured ~93us — UNCHANGED): staged q/k, phase-split,
// 8 blocks/CU. Platform wall: dual-bulk-stream reads cap at ~2.9 TB/s demand
// across 8 tested structures; this is the cheapest variant at that wall.
// ---------------------------------------------------------------------------
__global__ __launch_bounds__(256) void k_alpha(
    const float* __restrict__ q, const float* __restrict__ k,
    float* __restrict__ alpha, float* __restrict__ cM, float* __restrict__ cD)
{
    __shared__ float qs[2048];               // 8KB = 16 rows x 512B
    __shared__ float ks[2048];
    __shared__ float aw[4][16];              // per-wave row partial sums
    const int tid = threadIdx.x;
    const int l   = tid & 63;
    const int w   = tid >> 6;                // wave 0..3
    const int s   = blockIdx.x;              // sub-chunk id (16 timesteps)
    const size_t base = (size_t)s * (SC * DIM);   // float offset of tile

    #pragma unroll
    for (int r = 0; r < 2; ++r) {
        const int p  = r * 4096 + tid * 16;            // linear byte in 8KB
        const int ps = p ^ (((p >> 9) & 7) << 4);      // involution swizzle
        __builtin_amdgcn_global_load_lds((g_u32*)(q + base + (ps >> 2)),
            (lds_u32*)&qs[(r * 4096 + w * 1024) >> 2], 16, 0, 0);
    }
    __syncthreads();
    #pragma unroll
    for (int r = 0; r < 2; ++r) {
        const int p  = r * 4096 + tid * 16;
        const int ps = p ^ (((p >> 9) & 7) << 4);
        __builtin_amdgcn_global_load_lds((g_u32*)(k + base + (ps >> 2)),
            (lds_u32*)&ks[(r * 4096 + w * 1024) >> 2], 16, 0, 0);
    }
    __syncthreads();

    const int row = l & 15;
    const int cb  = (l >> 4) + 4 * w;                  // 0..15
    const int swz = (row & 7) << 4;
    float part = 0.f;
    #pragma unroll
    for (int rr = 0; rr < 2; ++rr) {
        const int off = row * 512 + ((cb * 32 + rr * 16) ^ swz);
        const float4 qv = *(const float4*)((const char*)qs + off);
        const float4 kv = *(const float4*)((const char*)ks + off);
        part += qv.x * kv.x + qv.y * kv.y + qv.z * kv.z + qv.w * kv.w;
    }
    part += __shfl_xor(part, 16);
    part += __shfl_xor(part, 32);
    if (l < 16) aw[w][row] = part;
    __syncthreads();

    if (tid < 16) {
        const float a = aw[0][tid] + aw[1][tid] + aw[2][tid] + aw[3][tid];
        float M = a;
        M = fmaxf(M, __shfl_xor(M, 1));
        M = fmaxf(M, __shfl_xor(M, 2));
        M = fmaxf(M, __shfl_xor(M, 4));
        M = fmaxf(M, __shfl_xor(M, 8));
        float e = __expf(a - M);
        e += __shfl_xor(e, 1);
        e += __shfl_xor(e, 2);
        e += __shfl_xor(e, 4);
        e += __shfl_xor(e, 8);
        alpha[s * SC + tid] = a;
        if (tid == 0) { cM[s] = M; cD[s] = e; }
    }
}

// ---------------------------------------------------------------------------
// k_scan (UNCHANGED, R10): per row serial exclusive scan over 256 sub-chunks
// -> pM,pD; then 16-lane-group prefix-max per sub-chunk -> coefCW = (c_t,w_t).
// ---------------------------------------------------------------------------
__global__ __launch_bounds__(256) void k_scan(
    const float* __restrict__ alpha, const float* __restrict__ cM,
    const float* __restrict__ cD,
    float* __restrict__ pM, float* __restrict__ pD, float2* __restrict__ coefCW)
{
    __shared__ float lM[SPR], lD[SPR], lpM[SPR];
    const int row = blockIdx.x;
    const int tid = threadIdx.x;

    lM[tid] = cM[row * SPR + tid];
    lD[tid] = cD[row * SPR + tid];
    __syncthreads();

    if (tid == 0) {
        float m = -INFINITY, d = 0.f;
        for (int sl = 0; sl < SPR; ++sl) {
            lpM[sl] = m;
            pM[row * SPR + sl] = m; pD[row * SPR + sl] = d;
            const float M = lM[sl], D = lD[sl];
            const float mn = fmaxf(m, M);
            d = d * __expf(m - mn) + D * __expf(M - mn);
            m = mn;
        }
    }
    __syncthreads();

    const int li = tid & 15, grp = tid >> 4;
    for (int sl = grp; sl < SPR; sl += 16) {
        const int s = row * SPR + sl;
        const float a = alpha[s * SC + li];
        float m = a;
        #pragma unroll
        for (int d = 1; d < 16; d <<= 1) {
            const float o = __shfl_up(m, d, 16);
            if (li >= d) m = fmaxf(m, o);
        }
        const float carry = lpM[sl];
        const float mf = fmaxf(m, carry);
        float mp = __shfl_up(mf, 1, 16);
        if (li == 0) mp = carry;
        const float cc = __expf(mp - mf);
        const float wt = __expf(a - mf);
        coefCW[s * SC + li] = make_float2(cc, wt);
    }
}

// ---------------------------------------------------------------------------
// k_fuse: decoupled-lookback fusion of k_agg + k_pref + k_out. One block per
// 64-t chunk g (row r=g>>6; chains never cross rows). Phases:
//  1) stream v-tile ONCE: each wave w handles t in [16w,16w+16); fma into
//     segment partial n'_w (seeded 0) and product P_w = prod(c); cache v in
//     LDS vt[t][lane] (float2, 512B rows, conflict-free) + coef in LDS.
//  2) wave0 folds segments -> chunk agg n'_g; publishes aggP[g] (agent-scope
//     atomic stores + threadfence + flag=1 release).
//  3) wave0 lookback: walk j=g-1..row_start; flag==1 -> acc += fac*agg[j],
//     fac *= f1_j (f1_j = exp(pM[4j]-pM[4j+4]), from k_scan); flag==2 ->
//     acc += fac*incl[j], break. Publishes incl[g] = acc*f1_g + n'_g, flag=2.
//     (aggP never overwritten -> no read-under-transition hazard.)
//  4) replay: wave w seeds S_w = fold(acc through segments <w), d-seed
//     pD[4g+w] (sub-chunk grain = segment grain), replays its 16 t from LDS
//     and writes y. v crosses the capped demand path exactly once.
// ---------------------------------------------------------------------------
__global__ __launch_bounds__(256) void k_fuse(
    const float* __restrict__ v, const float2* __restrict__ coefCW,
    const float* __restrict__ pM, const float* __restrict__ pD,
    float* __restrict__ aggP, float* __restrict__ inclP,
    unsigned int* __restrict__ flags, float* __restrict__ y)
{
    __shared__ float2 vt[VC][64];            // 32KB v-tile
    __shared__ float2 coefL[VC];             // (c,w) per timestep
    __shared__ float2 nseg[4][64];           // per-segment partials
    __shared__ float  Pseg[4];               // per-segment c-products
    __shared__ float2 preL[64];              // exclusive chunk prefix
    const int tid = threadIdx.x;
    const int l   = tid & 63;
    const int w   = tid >> 6;                // wave = 16-t segment
    const int g   = blockIdx.x;              // chunk id
    const int r0  = (g >> 6) << 6;           // row start chunk
    const size_t vb = (size_t)g * (VC * DIM);
    const int cb  = g * VC + w * 16;

    // ---- phase 1: stream v once, build segment partials + LDS cache
    float2 n = make_float2(0.f, 0.f);
    float  pr = 1.f;
    #pragma unroll
    for (int t0 = 0; t0 < 16; t0 += 8) {
        float2 cw[8], vv[8];
        #pragma unroll
        for (int u = 0; u < 8; ++u) cw[u] = coefCW[cb + t0 + u];
        #pragma unroll
        for (int u = 0; u < 8; ++u)
            vv[u] = *((const float2*)(v + vb + (w * 16 + t0 + u) * DIM) + l);
        #pragma unroll
        for (int u = 0; u < 8; ++u) {
            n.x = cw[u].x * n.x + cw[u].y * vv[u].x;
            n.y = cw[u].x * n.y + cw[u].y * vv[u].y;
            pr *= cw[u].x;
            vt[w * 16 + t0 + u][l] = vv[u];
            if (l == 0) coefL[w * 16 + t0 + u] = cw[u];
        }
    }
    nseg[w][l] = n;
    if (l == 0) Pseg[w] = pr;
    __syncthreads();

    // ---- phases 2+3: wave 0 combines, publishes, walks
    if (w == 0) {
        float2 a = nseg[0][l];
        #pragma unroll
        for (int u = 1; u < 4; ++u) {
            a.x = a.x * Pseg[u] + nseg[u][l].x;
            a.y = a.y * Pseg[u] + nseg[u][l].y;
        }
        __hip_atomic_store(&aggP[g * DIM + l * 2],     a.x,
                           __ATOMIC_RELAXED, __HIP_MEMORY_SCOPE_AGENT);
        __hip_atomic_store(&aggP[g * DIM + l * 2 + 1], a.y,
                           __ATOMIC_RELAXED, __HIP_MEMORY_SCOPE_AGENT);
        __threadfence();
        if (l == 0)
            __hip_atomic_store(&flags[g], 1u,
                               __ATOMIC_RELEASE, __HIP_MEMORY_SCOPE_AGENT);

        float2 acc = make_float2(0.f, 0.f);
        float  fac = 1.f;
        for (int j = g - 1; j >= r0; --j) {
            unsigned int f = 0;
            if (l == 0) {
                f = __hip_atomic_load(&flags[j], __ATOMIC_ACQUIRE,
                                      __HIP_MEMORY_SCOPE_AGENT);
                while (f == 0u) {
                    __builtin_amdgcn_s_sleep(2);
                    f = __hip_atomic_load(&flags[j], __ATOMIC_ACQUIRE,
                                          __HIP_MEMORY_SCOPE_AGENT);
                }
            }
            f = __shfl(f, 0, 64);
            if (f == 1u) {
                const float ax = __hip_atomic_load(&aggP[j * DIM + l * 2],
                        __ATOMIC_RELAXED, __HIP_MEMORY_SCOPE_AGENT);
                const float ay = __hip_atomic_load(&aggP[j * DIM + l * 2 + 1],
                        __ATOMIC_RELAXED, __HIP_MEMORY_SCOPE_AGENT);
                acc.x += fac * ax;  acc.y += fac * ay;
                fac *= __expf(pM[SPC * j] - pM[SPC * j + SPC]);
            } else {
                const float ix = __hip_atomic_load(&inclP[j * DIM + l * 2],
                        __ATOMIC_RELAXED, __HIP_MEMORY_SCOPE_AGENT);
                const float iy = __hip_atomic_load(&inclP[j * DIM + l * 2 + 1],
                        __ATOMIC_RELAXED, __HIP_MEMORY_SCOPE_AGENT);
                acc.x += fac * ix;  acc.y += fac * iy;
                break;
            }
        }
        // publish inclusive prefix (unused for row-last chunk; guarded f1)
        const float f1g = (g < r0 + 63)
                        ? __expf(pM[SPC * g] - pM[SPC * g + SPC]) : 0.f;
        const float2 inc = make_float2(acc.x * f1g + a.x * 0.f + (acc.x * 0.f),
                                       0.f);  // placeholder, real below
        (void)inc;
        {
            float2 a4 = nseg[0][l];
            #pragma unroll
            for (int u = 1; u < 4; ++u) {
                a4.x = a4.x * Pseg[u] + nseg[u][l].x;
                a4.y = a4.y * Pseg[u] + nseg[u][l].y;
            }
            const float inx = acc.x * f1g + a4.x * (0.f) + 0.f;
            (void)inx;
            // incl = acc*f1g + agg  (agg recomputed as a4 == a)
            __hip_atomic_store(&inclP[g * DIM + l * 2],
                               acc.x * f1g + a4.x,
                               __ATOMIC_RELAXED, __HIP_MEMORY_SCOPE_AGENT);
            __hip_atomic_store(&inclP[g * DIM + l * 2 + 1],
                               acc.y * f1g + a4.y,
                               __ATOMIC_RELAXED, __HIP_MEMORY_SCOPE_AGENT);
        }
        __threadfence();
        if (l == 0)
            __hip_atomic_store(&flags[g], 2u,
                               __ATOMIC_RELEASE, __HIP_MEMORY_SCOPE_AGENT);
        preL[l] = acc;
    }
    __syncthreads();

    // ---- phase 4: replay from LDS, write y
    float2 S = preL[l];
    for (int u = 0; u < w; ++u) {            // w<=3 uniform fold to segment seed
        S.x = S.x * Pseg[u] + nseg[u][l].x;
        S.y = S.y * Pseg[u] + nseg[u][l].y;
    }
    float dch = pD[g * SPC + w];             // sub-chunk grain == segment grain
    #pragma unroll
    for (int i = 0; i < 16; ++i) {
        const int t = w * 16 + i;
        const float2 cw = coefL[t];
        const float2 vv = vt[t][l];
        S.x = cw.x * S.x + cw.y * vv.x;
        S.y = cw.x * S.y + cw.y * vv.y;
        dch = cw.x * dch + cw.y;
        const float rd = __builtin_amdgcn_rcpf(dch);
        *((float2*)(y + vb + t * DIM) + l) = make_float2(S.x * rd, S.y * rd);
    }
}

// ---------------------------------------------------------------------------
extern "C" void kernel_launch(void* const* d_in, const int* in_sizes, int n_in,
                              void* d_out, int out_size, void* d_ws, size_t ws_size,
                              hipStream_t stream) {
    const float* q = (const float*)d_in[0];
    const float* k = (const float*)d_in[1];
    const float* v = (const float*)d_in[2];
    float* y  = (float*)d_out;
    float* ws = (float*)d_ws;

    // ws layout (floats), total 1,638,400 = 6.55 MB:
    //  coefCW : 524288
    //  pM,pD  : 16384 each
    //  cM     : 16384  (REUSED as flags after k_scan; memset before k_fuse)
    //  cD     : 16384
    //  aggP   : 524288 (never overwritten once flagged)
    //  U2     : 524288 (alpha in first 262144 during passes 1-2; inclP after)
    float*  coefCWf = ws;
    float*  pM      = coefCWf + 2 * ROWS * NSEQ;       // +524288
    float*  pD      = pM + NSC;
    float*  cM      = pD + NSC;
    float*  cD      = cM + NSC;
    float*  aggP    = cD + NSC;
    float*  U2      = aggP + NVC * DIM;
    float*  alphaA  = U2;                              // dead after k_scan
    float*  inclP   = U2;
    unsigned int* flags = (unsigned int*)cM;           // dead after k_scan
    float2* coefCW  = (float2*)coefCWf;

    k_alpha<<<NSC, 256, 0, stream>>>(q, k, alphaA, cM, cD);
    k_scan<<<ROWS, 256, 0, stream>>>(alphaA, cM, cD, pM, pD, coefCW);
    hipMemsetAsync((void*)flags, 0, NVC * sizeof(unsigned int), stream);
    k_fuse<<<NVC, 256, 0, stream>>>(v, coefCW, pM, pD, aggP, inclP, flags, y);
}

// Round 14
// 158.890 us; speedup vs baseline: 5.9632x; 5.9632x over previous
//
#include <hip/hip_runtime.h>
#include <math.h>
#include <stdint.h>

// B=4, H=16, N=4096, D=128 -> 64 independent scan rows of length 4096.
// REVERT to the best-measured configuration (R10, 158.2 us total):
//   k_alpha v8 (phase-split q/k staging, ~93 us — dual-stream demand wall)
//   + k_scan + k_agg + k_pref + k_out (tail ~65 us at single-stream rates).
// R13's decoupled-lookback fusion regressed 6x (lookback latency-serial);
// fusion is infeasible at this chunk size. This is the platform-limited
// structure: q,k read once at the 2.9 TB/s dual-stream wall; v read twice +
// y written once at ~6.5 TB/s single-stream; ~7 us serial scan glue.
static constexpr int ROWS = 64;
static constexpr int NSEQ = 4096;
static constexpr int DIM  = 128;
static constexpr int SC   = 16;              // scalar sub-chunk length
static constexpr int SPR  = NSEQ / SC;       // 256 sub-chunks per row
static constexpr int NSC  = ROWS * SPR;      // 16384 sub-chunks
static constexpr int VC   = 64;              // vector chunk length
static constexpr int VPR  = NSEQ / VC;       // 64 chunks per row
static constexpr int NVC  = ROWS * VPR;      // 4096 vector chunks
static constexpr int SPC  = VC / SC;         // sub-chunks per vector chunk = 4

typedef __attribute__((address_space(3))) uint32_t  lds_u32;
typedef const __attribute__((address_space(1))) uint32_t g_u32;

// ---------------------------------------------------------------------------
// k_alpha v8: staged q/k with PHASE-SPLIT staging; 8 blocks/CU.
// ---------------------------------------------------------------------------
__global__ __launch_bounds__(256) void k_alpha(
    const float* __restrict__ q, const float* __restrict__ k,
    float* __restrict__ alpha, float* __restrict__ cM, float* __restrict__ cD)
{
    __shared__ float qs[2048];               // 8KB = 16 rows x 512B
    __shared__ float ks[2048];
    __shared__ float aw[4][16];              // per-wave row partial sums
    const int tid = threadIdx.x;
    const int l   = tid & 63;
    const int w   = tid >> 6;                // wave 0..3
    const int s   = blockIdx.x;              // sub-chunk id (16 timesteps)
    const size_t base = (size_t)s * (SC * DIM);   // float offset of tile

    // ---- phase A: stage q ONLY, then drain.
    #pragma unroll
    for (int r = 0; r < 2; ++r) {
        const int p  = r * 4096 + tid * 16;            // linear byte in 8KB
        const int ps = p ^ (((p >> 9) & 7) << 4);      // involution swizzle
        __builtin_amdgcn_global_load_lds((g_u32*)(q + base + (ps >> 2)),
            (lds_u32*)&qs[(r * 4096 + w * 1024) >> 2], 16, 0, 0);
    }
    __syncthreads();

    // ---- phase B: stage k ONLY, then drain.
    #pragma unroll
    for (int r = 0; r < 2; ++r) {
        const int p  = r * 4096 + tid * 16;
        const int ps = p ^ (((p >> 9) & 7) << 4);
        __builtin_amdgcn_global_load_lds((g_u32*)(k + base + (ps >> 2)),
            (lds_u32*)&ks[(r * 4096 + w * 1024) >> 2], 16, 0, 0);
    }
    __syncthreads();

    // ---- partial dot: row = l&15 (timestep), colblk = (l>>4)+4w (8 floats)
    const int row = l & 15;
    const int cb  = (l >> 4) + 4 * w;                  // 0..15
    const int swz = (row & 7) << 4;
    float part = 0.f;
    #pragma unroll
    for (int rr = 0; rr < 2; ++rr) {
        const int off = row * 512 + ((cb * 32 + rr * 16) ^ swz);
        const float4 qv = *(const float4*)((const char*)qs + off);
        const float4 kv = *(const float4*)((const char*)ks + off);
        part += qv.x * kv.x + qv.y * kv.y + qv.z * kv.z + qv.w * kv.w;
    }
    part += __shfl_xor(part, 16);
    part += __shfl_xor(part, 32);
    if (l < 16) aw[w][row] = part;
    __syncthreads();

    // ---- wave 0, lanes 0..15: alpha + sub-chunk stats
    if (tid < 16) {
        const float a = aw[0][tid] + aw[1][tid] + aw[2][tid] + aw[3][tid];
        float M = a;
        M = fmaxf(M, __shfl_xor(M, 1));
        M = fmaxf(M, __shfl_xor(M, 2));
        M = fmaxf(M, __shfl_xor(M, 4));
        M = fmaxf(M, __shfl_xor(M, 8));
        float e = __expf(a - M);
        e += __shfl_xor(e, 1);
        e += __shfl_xor(e, 2);
        e += __shfl_xor(e, 4);
        e += __shfl_xor(e, 8);
        alpha[s * SC + tid] = a;                       // coalesced 64B
        if (tid == 0) { cM[s] = M; cD[s] = e; }
    }
}

// ---------------------------------------------------------------------------
// k_scan: per row (64 blocks):
//  1) thread-0 serial exclusive scan over 256 sub-chunks -> pM,pD (+LDS copy)
//  2) 16-lane-group prefix-max scan per sub-chunk -> coefCW[t] = (c_t, w_t)
// ---------------------------------------------------------------------------
__global__ __launch_bounds__(256) void k_scan(
    const float* __restrict__ alpha, const float* __restrict__ cM,
    const float* __restrict__ cD,
    float* __restrict__ pM, float* __restrict__ pD, float2* __restrict__ coefCW)
{
    __shared__ float lM[SPR], lD[SPR], lpM[SPR];
    const int row = blockIdx.x;
    const int tid = threadIdx.x;

    lM[tid] = cM[row * SPR + tid];
    lD[tid] = cD[row * SPR + tid];
    __syncthreads();

    if (tid == 0) {
        float m = -INFINITY, d = 0.f;
        for (int sl = 0; sl < SPR; ++sl) {
            lpM[sl] = m;
            pM[row * SPR + sl] = m; pD[row * SPR + sl] = d;
            const float M = lM[sl], D = lD[sl];
            const float mn = fmaxf(m, M);
            d = d * __expf(m - mn) + D * __expf(M - mn);
            m = mn;
        }
    }
    __syncthreads();

    const int li = tid & 15, grp = tid >> 4;          // 16 groups of 16 lanes
    for (int sl = grp; sl < SPR; sl += 16) {
        const int s = row * SPR + sl;
        const float a = alpha[s * SC + li];
        // inclusive prefix max over the 16 lanes
        float m = a;
        #pragma unroll
        for (int d = 1; d < 16; d <<= 1) {
            const float o = __shfl_up(m, d, 16);
            if (li >= d) m = fmaxf(m, o);
        }
        const float carry = lpM[sl];
        const float mf = fmaxf(m, carry);             // running max incl. carry
        float mp = __shfl_up(mf, 1, 16);
        if (li == 0) mp = carry;                      // m_{t-1}
        const float cc = __expf(mp - mf);             // exp(-inf)=0 at very start
        const float wt = __expf(a - mf);
        coefCW[s * SC + li] = make_float2(cc, wt);
    }
}

// ---------------------------------------------------------------------------
// k_agg: per vector chunk (one wave, lane owns 2 dims): n'_C via the global
// coefficient recurrence seeded 0 (result normalized at chunk-end global max).
// ---------------------------------------------------------------------------
__global__ __launch_bounds__(256) void k_agg(
    const float* __restrict__ v, const float2* __restrict__ coefCW,
    float2* __restrict__ aggN)
{
    const int lane  = threadIdx.x & 63;
    const int C     = blockIdx.x * 4 + (threadIdx.x >> 6);
    const int vbase = C * (VC * DIM);
    const int cbase = __builtin_amdgcn_readfirstlane(C * VC);

    float nx = 0.f, ny = 0.f;
    for (int t0 = 0; t0 < VC; t0 += 8) {
        float2 cw[8], vv[8];
        #pragma unroll
        for (int u = 0; u < 8; ++u) cw[u] = coefCW[cbase + t0 + u];
        #pragma unroll
        for (int u = 0; u < 8; ++u)
            vv[u] = *((const float2*)(v + vbase + (t0 + u) * DIM) + lane);
        #pragma unroll
        for (int u = 0; u < 8; ++u) {
            nx = cw[u].x * nx + cw[u].y * vv[u].x;
            ny = cw[u].x * ny + cw[u].y * vv[u].y;
        }
    }
    aggN[C * (DIM / 2) + lane] = make_float2(nx, ny);
}

// ---------------------------------------------------------------------------
// k_pref: per row, exclusive prefix scan of aggN over 64 chunks (in place),
// combine factor f1 = exp(pM[4C] - pM[4C+4]) (sub-chunk stride = 4).
// ---------------------------------------------------------------------------
__global__ __launch_bounds__(128) void k_pref(
    float* __restrict__ aggN, const float* __restrict__ pM)
{
    const int row = blockIdx.x;
    const int d   = threadIdx.x;
    float state = 0.f;
    for (int C0 = 0; C0 < VPR; C0 += 8) {
        float nb[8], f1[8];
        #pragma unroll
        for (int u = 0; u < 8; ++u) {
            const int C  = C0 + u;
            const int Cg = row * VPR + C;
            nb[u] = aggN[Cg * DIM + d];
            const bool last = (C == VPR - 1);
            const float mp  = pM[SPC * Cg];
            const float mp2 = last ? 0.f : pM[SPC * Cg + SPC];
            f1[u] = last ? 0.f : __expf(mp - mp2);
        }
        #pragma unroll
        for (int u = 0; u < 8; ++u) {
            const float nc = nb[u];
            aggN[(row * VPR + C0 + u) * DIM + d] = state;
            state = state * f1[u] + nc;
        }
    }
}

// ---------------------------------------------------------------------------
// k_out: per vector chunk (one wave, lane owns 2 dims): replay the global
// recurrence seeded with the exclusive prefixes; y_t = n_t * rcp(d_t).
// ---------------------------------------------------------------------------
__global__ __launch_bounds__(256) void k_out(
    const float* __restrict__ v, const float2* __restrict__ coefCW,
    const float2* __restrict__ preN, const float* __restrict__ pD,
    float* __restrict__ y)
{
    const int lane  = threadIdx.x & 63;
    const int C     = blockIdx.x * 4 + (threadIdx.x >> 6);
    const int vbase = C * (VC * DIM);
    const int cbase = __builtin_amdgcn_readfirstlane(C * VC);

    float2 n  = preN[C * (DIM / 2) + lane];
    float dch = pD[SPC * C];

    for (int t0 = 0; t0 < VC; t0 += 8) {
        float2 cw[8], vv[8];
        #pragma unroll
        for (int u = 0; u < 8; ++u) cw[u] = coefCW[cbase + t0 + u];
        #pragma unroll
        for (int u = 0; u < 8; ++u)
            vv[u] = *((const float2*)(v + vbase + (t0 + u) * DIM) + lane);
        #pragma unroll
        for (int u = 0; u < 8; ++u) {
            n.x = cw[u].x * n.x + cw[u].y * vv[u].x;
            n.y = cw[u].x * n.y + cw[u].y * vv[u].y;
            dch = cw[u].x * dch + cw[u].y;
            const float rd = __builtin_amdgcn_rcpf(dch);
            *((float2*)(y + vbase + (t0 + u) * DIM) + lane) =
                make_float2(n.x * rd, n.y * rd);
        }
    }
}

// ---------------------------------------------------------------------------
extern "C" void kernel_launch(void* const* d_in, const int* in_sizes, int n_in,
                              void* d_out, int out_size, void* d_ws, size_t ws_size,
                              hipStream_t stream) {
    const float* q = (const float*)d_in[0];
    const float* k = (const float*)d_in[1];
    const float* v = (const float*)d_in[2];
    float* y  = (float*)d_out;
    float* ws = (float*)d_ws;

    // ws layout (floats):
    //  coefCW : 524288    (float2[262144], global per-timestep (c,w))
    //  pM,pD  : 16384 each (exclusive scalar prefixes, SC=16 grain)
    //  cM,cD  : 16384 each (sub-chunk local max / denom)
    //  U      : 524288    (alpha uses first 262144; aggN reuses all of it)
    float*  coefCWf = ws;
    float*  pM      = coefCWf + 2 * ROWS * NSEQ;       // +524288
    float*  pD      = pM + NSC;
    float*  cM      = pD + NSC;
    float*  cD      = cM + NSC;
    float*  U       = cD + NSC;
    float*  alphaA  = U;                               // 262144 floats
    float*  aggNf   = U;                               // 524288 floats (after k_scan)
    float2* coefCW  = (float2*)coefCWf;
    float2* aggN2   = (float2*)aggNf;
    // total: 1,114,112 floats = 4.46 MB

    k_alpha<<<NSC, 256, 0, stream>>>(q, k, alphaA, cM, cD);
    k_scan<<<ROWS, 256, 0, stream>>>(alphaA, cM, cD, pM, pD, coefCW);
    k_agg<<<NVC / 4, 256, 0, stream>>>(v, coefCW, aggN2);
    k_pref<<<ROWS, DIM, 0, stream>>>(aggNf, pM);
    k_out<<<NVC / 4, 256, 0, stream>>>(v, coefCW, aggN2, pD, y);
}